// Round 3
// baseline (508.939 us; speedup 1.0000x reference)
//
#include <hip/hip_runtime.h>
#include <hip/hip_bf16.h>

#define B_ 32
#define S_ 4096
#define H_ 512
#define M_ (B_ * S_)   // 131072
#define L_ 2

typedef __bf16 bf16;
typedef bf16 bf16x8 __attribute__((ext_vector_type(8)));
typedef float floatx2 __attribute__((ext_vector_type(2)));
typedef float floatx4 __attribute__((ext_vector_type(4)));
typedef float floatx16 __attribute__((ext_vector_type(16)));

__device__ inline bf16 f2b(float f) { return (bf16)f; }

__device__ inline float fast_tanh(float x) {
    float xc = fminf(15.0f, fmaxf(-15.0f, x));
    float e = __expf(2.0f * xc);
    return (e - 1.0f) * __builtin_amdgcn_rcpf(e + 1.0f);
}

// ---------------- kernel 0: W (H,H) fp32 -> bf16 MFMA-fragment-major ----------------
// Fragment (nt, ks) = B-operand of mfma_32x32x16 for n-rows [nt*32, nt*32+32),
// k [ks*16, ks*16+16). Stored as 64 lanes x 16B contiguous (1 KB):
// lane l holds W[nt*32 + (l&31)][ks*16 + (l>>5)*8 .. +8).
__global__ __launch_bounds__(256) void convert_Wfrag(const float* __restrict__ W,
                                                     bf16* __restrict__ Wf) {
    int gid  = blockIdx.x * 256 + threadIdx.x;   // 0..32767
    int lane = gid & 63;
    int ks   = (gid >> 6) & 31;
    int nt   = gid >> 11;                        // 0..15
    int row  = nt * 32 + (lane & 31);
    int col  = ks * 16 + (lane >> 5) * 8;
    const float* src = W + (size_t)row * H_ + col;
    floatx4 f0 = *(const floatx4*)src;
    floatx4 f1 = *(const floatx4*)(src + 4);
    bf16x8 p = { f2b(f0[0]), f2b(f0[1]), f2b(f0[2]), f2b(f0[3]),
                 f2b(f1[0]), f2b(f1[1]), f2b(f1[2]), f2b(f1[3]) };
    *(bf16x8*)(Wf + (size_t)gid * 8) = p;
}

// ---------------- kernel 1: fused scores + partial context (flash-style) --------
// 16 waves (1024 threads), wave w owns n in [w*32, w*32+32) -> acc[2] only
// (32 AGPR/wave), ~120 regs total -> 4 waves/SIMD -> 16 waves/CU.
// scores[m] = sum_n tanh((out @ W^T)[m,n] + b[n] + hlast[batch,n]) * v[n]
// then local softmax numerators + partial context from L2/L3-hot out rows.
#define MT 64

__global__ __launch_bounds__(1024, 4) void scores_kernel(
    const float* __restrict__ outT,   // (M, 512)
    const bf16*  __restrict__ Wf,     // fragment-major W (512 KB)
    const float* __restrict__ bias,   // (512)
    const float* __restrict__ hidden, // (L, B, 512)
    const float* __restrict__ v,      // (512)
    float* __restrict__ scores,       // (M)
    float* __restrict__ pc,           // (M/MT, 512) partial context
    float* __restrict__ lmaxg,        // (M/MT)
    float* __restrict__ lsumg)        // (M/MT)
{
    __shared__ bf16 Alds[MT * 512];   // 64 KB, fragment-major

    const int tid  = threadIdx.x;
    const int wave = tid >> 6;        // 0..15 == nt owned by this wave
    const int lane = tid & 63;
    const int l31  = lane & 31;
    const int half = lane >> 5;       // 0..1

    const int m0    = blockIdx.x * MT;
    const int batch = m0 >> 12;       // m0 / S_

    // per-lane Wf base: frag(nt, ks) at nt*16384 + ks*512 elements
    const bf16* wf = Wf + (size_t)wave * 16384 + lane * 8;

    // B-ring prologue issued BEFORE staging: L2/L3 latency overlaps HBM stage
    bf16x8 bb[4];
    #pragma unroll
    for (int p = 0; p < 4; ++p)
        bb[p] = *(const bf16x8*)(wf + p * 512);

    // ---- stage A: 64 rows x 512 fp32 -> bf16 fragment-major LDS.
    // A-frag (mt, ks): lane l holds A[mt*32 + (l&31)][ks*16 + (l>>5)*8 ..+8)
    // at slot = (l>>5)*32 + ((l&31) + ks)&31  (rotation kills write conflicts).
    {
        const floatx4* src = (const floatx4*)(outT + (size_t)m0 * H_);
        #pragma unroll
        for (int it = 0; it < 4; ++it) {
            int idx = it * 1024 + tid;    // 16B-block index: r = row, j = k-block
            int r   = idx >> 6;
            int j   = idx & 63;
            floatx4 f0 = __builtin_nontemporal_load(src + idx * 2);
            floatx4 f1 = __builtin_nontemporal_load(src + idx * 2 + 1);
            bf16x8 p = { f2b(f0[0]), f2b(f0[1]), f2b(f0[2]), f2b(f0[3]),
                         f2b(f1[0]), f2b(f1[1]), f2b(f1[2]), f2b(f1[3]) };
            int frag = (r >> 5) * 32 + (j >> 1);
            int slot = (j & 1) * 32 + ((r + (j >> 1)) & 31);
            *(bf16x8*)&Alds[frag * 512 + slot * 8] = p;
        }
    }
    __syncthreads();

    floatx16 acc[2];
    #pragma unroll
    for (int mt = 0; mt < 2; ++mt) acc[mt] = (floatx16)(0.0f);

    // depth-2 A register ping-pong (slot = ks & 1)
    bf16x8 aa[2][2];
    #pragma unroll
    for (int mt = 0; mt < 2; ++mt)
        aa[0][mt] = *(const bf16x8*)
            &Alds[(mt * 32 + 0) * 512 + (half * 32 + (l31 & 31)) * 8];

    #pragma unroll
    for (int ks = 0; ks < 32; ++ks) {
        const int cur = ks & 3;
        const int ap  = ks & 1;
        // A-prefetch for ks+1 FIRST: ds_read latency hidden behind the MFMAs
        if (ks < 31) {
            const int rot = (l31 + ks + 1) & 31;
            #pragma unroll
            for (int mt = 0; mt < 2; ++mt)
                aa[ap ^ 1][mt] = *(const bf16x8*)
                    &Alds[(mt * 32 + ks + 1) * 512 + (half * 32 + rot) * 8];
        }
        #pragma unroll
        for (int mt = 0; mt < 2; ++mt)
            acc[mt] = __builtin_amdgcn_mfma_f32_32x32x16_bf16(
                aa[ap][mt], bb[cur], acc[mt], 0, 0, 0);
        // B-prefetch for ks+4 into the slot just consumed
        if (ks < 28)
            bb[cur] = *(const bf16x8*)(wf + (ks + 4) * 512);
    }

    // ---- epilogue: tanh(acc + b + hlast) * v, reduce over this wave's 32 cols.
    // C/D of 32x32: col = lane&31, row = (reg&3) + 8*(reg>>2) + 4*(lane>>5).
    const float* hlast = hidden + (size_t)((L_ - 1) * B_ + batch) * H_;
    const int n  = wave * 32 + l31;
    const float bn = bias[n] + hlast[n];
    const float vn = v[n];

    __syncthreads();                 // done reading Alds; reuse as scratch
    float*   sred  = (float*)Alds;            // 16 waves x 64 rows = 4 KB
    float*   pbuf  = sred + 1024;             // 64 softmax numerators
    floatx4* pvred = (floatx4*)(pbuf + 64);   // 8 x 128 floatx4 = 16 KB

    #pragma unroll
    for (int mt = 0; mt < 2; ++mt)
        #pragma unroll
        for (int rg = 0; rg < 16; ++rg) {
            float s = fast_tanh(acc[mt][rg] + bn) * vn;
            s += __shfl_xor(s, 1);
            s += __shfl_xor(s, 2);
            s += __shfl_xor(s, 4);
            s += __shfl_xor(s, 8);
            s += __shfl_xor(s, 16);
            if (l31 == 0) {
                int row = (rg & 3) + 8 * (rg >> 2) + 4 * half;
                sred[wave * 64 + mt * 32 + row] = s;
            }
        }
    __syncthreads();

    // ---- flash-style local softmax numerators on the block's 64 rows ----
    if (tid < 64) {   // wave 0, full 64-lane wave
        float sc = 0.0f;
        #pragma unroll
        for (int w = 0; w < 16; ++w) sc += sred[w * 64 + tid];
        scores[m0 + tid] = sc;
        float mx = sc;
        #pragma unroll
        for (int off = 32; off >= 1; off >>= 1) mx = fmaxf(mx, __shfl_xor(mx, off));
        float p = __expf(sc - mx);
        pbuf[tid] = p;
        float sm = p;
        #pragma unroll
        for (int off = 32; off >= 1; off >>= 1) sm += __shfl_xor(sm, off);
        if (tid == 0) { lmaxg[blockIdx.x] = mx; lsumg[blockIdx.x] = sm; }
    }
    __syncthreads();

    // ---- partial context: pc[h] = sum_{s<64} p_s * out[m0+s][h] (fp32).
    // 8-way s-split across 1024 threads; NONTEMPORAL so the re-read does not
    // evict Wf from L2 (data is read-once, already L2/L3-hot from staging).
    {
        const int c4 = tid & 127;        // float4 column
        const int sg = tid >> 7;         // 0..7 -> 8-row group
        const floatx4* op = (const floatx4*)(outT + (size_t)(m0 + sg * 8) * H_) + c4;
        floatx4 a = (floatx4)(0.0f);
        #pragma unroll
        for (int j = 0; j < 8; ++j)
            a += pbuf[sg * 8 + j] * __builtin_nontemporal_load(op + (size_t)j * 128);
        pvred[sg * 128 + c4] = a;
    }
    __syncthreads();
    if (tid < 128) {
        floatx4 r = (floatx4)(0.0f);
        #pragma unroll
        for (int sg = 0; sg < 8; ++sg) r += pvred[sg * 128 + tid];
        *(floatx4*)&pc[(size_t)blockIdx.x * H_ + tid * 4] = r;
    }
}

// ---------------- kernel 2: softmax over S per batch (writes attn output) -------
__global__ __launch_bounds__(256) void softmax_kernel(const float* __restrict__ scores,
                                                      float* __restrict__ attn) {
    __shared__ float red[4];
    int b = blockIdx.x, tid = threadIdx.x;
    const float* row = scores + (size_t)b * S_;
    float vals[16];
    float mx = -3.4e38f;
    #pragma unroll
    for (int i = 0; i < 16; ++i) { vals[i] = row[i * 256 + tid]; mx = fmaxf(mx, vals[i]); }
    #pragma unroll
    for (int off = 32; off >= 1; off >>= 1) mx = fmaxf(mx, __shfl_xor(mx, off));
    if ((tid & 63) == 0) red[tid >> 6] = mx;
    __syncthreads();
    mx = fmaxf(fmaxf(red[0], red[1]), fmaxf(red[2], red[3]));
    __syncthreads();
    float sum = 0.f;
    #pragma unroll
    for (int i = 0; i < 16; ++i) { vals[i] = __expf(vals[i] - mx); sum += vals[i]; }
    #pragma unroll
    for (int off = 32; off >= 1; off >>= 1) sum += __shfl_xor(sum, off);
    if ((tid & 63) == 0) red[tid >> 6] = sum;
    __syncthreads();
    float inv = 1.0f / (red[0] + red[1] + red[2] + red[3]);
    #pragma unroll
    for (int i = 0; i < 16; ++i) attn[(size_t)b * S_ + i * 256 + tid] = vals[i] * inv;
}

// ---------------- kernel 3: combine 64 per-block partials -> ctx ----------------
// ctx[b][h] = ( sum_j exp(lmax_j - gmax) * pc[b*64+j][h] ) / gsum,
// gsum = sum_j exp(lmax_j - gmax) * lsum_j.   Reads only 4 MB total.
__global__ __launch_bounds__(256) void context_final(const float* __restrict__ pc,
                                                     const float* __restrict__ lmaxg,
                                                     const float* __restrict__ lsumg,
                                                     float* __restrict__ ctx) {
    __shared__ float e_sh[64];
    __shared__ float inv_sh;
    int b = blockIdx.x, tid = threadIdx.x;
    if (tid < 64) {    // wave 0: 64 per-block stats of this batch
        float lm = lmaxg[b * 64 + tid];
        float mx = lm;
        #pragma unroll
        for (int off = 32; off >= 1; off >>= 1) mx = fmaxf(mx, __shfl_xor(mx, off));
        float e = __expf(lm - mx);
        e_sh[tid] = e;
        float gs = e * lsumg[b * 64 + tid];
        #pragma unroll
        for (int off = 32; off >= 1; off >>= 1) gs += __shfl_xor(gs, off);
        if (tid == 0) inv_sh = 1.0f / gs;
    }
    __syncthreads();
    float inv = inv_sh;
    const floatx2* pp = (const floatx2*)(pc + (size_t)b * 64 * H_) + tid;
    floatx2 a = (floatx2)(0.0f);
    #pragma unroll 8
    for (int j = 0; j < 64; ++j) {
        floatx2 q = __builtin_nontemporal_load(pp + (size_t)j * 256);
        a += e_sh[j] * q;
    }
    floatx2 r = a * inv;
    *(floatx2*)&ctx[(size_t)b * H_ + tid * 2] = r;
}

extern "C" void kernel_launch(void* const* d_in, const int* in_sizes, int n_in,
                              void* d_out, int out_size, void* d_ws, size_t ws_size,
                              hipStream_t stream) {
    const float* outT   = (const float*)d_in[0];  // (B,S,H)
    const float* hidden = (const float*)d_in[1];  // (L,B,H)
    const float* W      = (const float*)d_in[2];  // (H,H)
    const float* bias   = (const float*)d_in[3];  // (H)
    const float* v      = (const float*)d_in[4];  // (H)

    float* ctx    = (float*)d_out;                // (B,H)
    float* attn   = (float*)d_out + B_ * H_;      // (B,S)

    const int NBLK = M_ / MT;                     // 2048
    float* scores = (float*)d_ws;                                   // 512 KB
    bf16*  Wf     = (bf16*)((char*)d_ws + (size_t)M_ * 4);          // 512 KB
    float* pc     = (float*)((char*)d_ws + (size_t)M_ * 4 + (size_t)H_ * H_ * 2); // 4 MB
    float* lmaxg  = pc + (size_t)NBLK * H_;                         // 8 KB
    float* lsumg  = lmaxg + NBLK;                                   // 8 KB

    convert_Wfrag<<<128, 256, 0, stream>>>(W, Wf);
    scores_kernel<<<NBLK, 1024, 0, stream>>>(outT, Wf, bias, hidden, v,
                                             scores, pc, lmaxg, lsumg);
    softmax_kernel<<<B_, 256, 0, stream>>>(scores, attn);
    context_final<<<B_, 256, 0, stream>>>(pc, lmaxg, lsumg, ctx);
}

// Round 7
// 506.621 us; speedup vs baseline: 1.0046x; 1.0046x over previous
//
#include <hip/hip_runtime.h>
#include <hip/hip_bf16.h>

#define B_ 32
#define S_ 4096
#define H_ 512
#define M_ (B_ * S_)   // 131072
#define L_ 2

typedef __bf16 bf16;
typedef bf16 bf16x8 __attribute__((ext_vector_type(8)));
typedef float floatx2 __attribute__((ext_vector_type(2)));
typedef float floatx4 __attribute__((ext_vector_type(4)));
typedef float floatx16 __attribute__((ext_vector_type(16)));

__device__ inline bf16 f2b(float f) { return (bf16)f; }

__device__ inline float fast_tanh(float x) {
    float xc = fminf(15.0f, fmaxf(-15.0f, x));
    float e = __expf(2.0f * xc);
    return (e - 1.0f) * __builtin_amdgcn_rcpf(e + 1.0f);
}

// ---------------- kernel 0: W (H,H) fp32 -> bf16 MFMA-fragment-major ----------------
// Fragment (nt, ks) = B-operand of mfma_32x32x16 for n-rows [nt*32, nt*32+32),
// k [ks*16, ks*16+16). Stored as 64 lanes x 16B contiguous (1 KB):
// lane l holds W[nt*32 + (l&31)][ks*16 + (l>>5)*8 .. +8).
__global__ __launch_bounds__(256) void convert_Wfrag(const float* __restrict__ W,
                                                     bf16* __restrict__ Wf) {
    int gid  = blockIdx.x * 256 + threadIdx.x;   // 0..32767
    int lane = gid & 63;
    int ks   = (gid >> 6) & 31;
    int nt   = gid >> 11;                        // 0..15
    int row  = nt * 32 + (lane & 31);
    int col  = ks * 16 + (lane >> 5) * 8;
    const float* src = W + (size_t)row * H_ + col;
    floatx4 f0 = *(const floatx4*)src;
    floatx4 f1 = *(const floatx4*)(src + 4);
    bf16x8 p = { f2b(f0[0]), f2b(f0[1]), f2b(f0[2]), f2b(f0[3]),
                 f2b(f1[0]), f2b(f1[1]), f2b(f1[2]), f2b(f1[3]) };
    *(bf16x8*)(Wf + (size_t)gid * 8) = p;
}

// ---------------- kernel 1: fused scores + partial context (flash-style) --------
// 16 waves (1024 threads), wave w owns n in [w*32, w*32+32) -> acc[2] (32 AGPR).
// K-loop pipelining: depth-8 B register ring (covers L2/L3 latency), depth-4 A
// ring with prefetch distance 2 (covers ds_read latency), per-wave K-offset
// (kk = (ks + 2*wave) & 31) so waves walk different frags -> no lockstep convoy.
// NOTE: B-prefetch MUST come after the MFMAs — with distance 8 on a depth-8
// ring it refills the slot just consumed ((ks+8)&7 == ks&7).
#define MT 64

__global__ __launch_bounds__(1024, 4) void scores_kernel(
    const float* __restrict__ outT,   // (M, 512)
    const bf16*  __restrict__ Wf,     // fragment-major W (512 KB)
    const float* __restrict__ bias,   // (512)
    const float* __restrict__ hidden, // (L, B, 512)
    const float* __restrict__ v,      // (512)
    float* __restrict__ scores,       // (M)
    float* __restrict__ pc,           // (M/MT, 512) partial context
    float* __restrict__ lmaxg,        // (M/MT)
    float* __restrict__ lsumg)        // (M/MT)
{
    __shared__ bf16 Alds[MT * 512];   // 64 KB, fragment-major

    const int tid  = threadIdx.x;
    const int wave = tid >> 6;        // 0..15 == nt owned by this wave
    const int lane = tid & 63;
    const int l31  = lane & 31;
    const int half = lane >> 5;       // 0..1

    const int m0    = blockIdx.x * MT;
    const int batch = m0 >> 12;       // m0 / S_
    const int koff  = (wave * 2) & 31;  // per-wave K rotation

    // per-lane Wf base: frag(nt, ks) at nt*16384 + ks*512 elements
    const bf16* wf = Wf + (size_t)wave * 16384 + lane * 8;

    // B-ring prologue (depth 8) issued BEFORE staging: L2 latency overlaps stage
    bf16x8 bb[8];
    #pragma unroll
    for (int p = 0; p < 8; ++p)
        bb[p] = *(const bf16x8*)(wf + ((p + koff) & 31) * 512);

    // ---- stage A: 64 rows x 512 fp32 -> bf16 fragment-major LDS.
    // A-frag (mt, ks): lane l holds A[mt*32 + (l&31)][ks*16 + (l>>5)*8 ..+8)
    // at slot = (l>>5)*32 + ((l&31) + ks)&31  (rotation kills write conflicts).
    {
        const floatx4* src = (const floatx4*)(outT + (size_t)m0 * H_);
        #pragma unroll
        for (int it = 0; it < 4; ++it) {
            int idx = it * 1024 + tid;    // 16B-block index: r = row, j = k-block
            int r   = idx >> 6;
            int j   = idx & 63;
            floatx4 f0 = __builtin_nontemporal_load(src + idx * 2);
            floatx4 f1 = __builtin_nontemporal_load(src + idx * 2 + 1);
            bf16x8 p = { f2b(f0[0]), f2b(f0[1]), f2b(f0[2]), f2b(f0[3]),
                         f2b(f1[0]), f2b(f1[1]), f2b(f1[2]), f2b(f1[3]) };
            int frag = (r >> 5) * 32 + (j >> 1);
            int slot = (j & 1) * 32 + ((r + (j >> 1)) & 31);
            *(bf16x8*)&Alds[frag * 512 + slot * 8] = p;
        }
    }
    __syncthreads();

    floatx16 acc[2];
    acc[0] = (floatx16)(0.0f);
    acc[1] = (floatx16)(0.0f);

    // depth-4 A ring, prefetch distance 2 (two ds_reads in flight per mt)
    bf16x8 aa[4][2];
    #pragma unroll
    for (int p = 0; p < 2; ++p) {
        const int kk = (p + koff) & 31;
        const int rot = (l31 + kk) & 31;
        #pragma unroll
        for (int mt = 0; mt < 2; ++mt)
            aa[p][mt] = *(const bf16x8*)
                &Alds[(mt * 32 + kk) * 512 + (half * 32 + rot) * 8];
    }

    #pragma unroll
    for (int ks = 0; ks < 32; ++ks) {
        const int bcur = ks & 7;
        const int acur = ks & 3;
        // A-prefetch for ks+2: ds_read latency hidden behind 2 ksteps of issue
        if (ks < 30) {
            const int kk = (ks + 2 + koff) & 31;
            const int rot = (l31 + kk) & 31;
            #pragma unroll
            for (int mt = 0; mt < 2; ++mt)
                aa[(ks + 2) & 3][mt] = *(const bf16x8*)
                    &Alds[(mt * 32 + kk) * 512 + (half * 32 + rot) * 8];
        }
        acc[0] = __builtin_amdgcn_mfma_f32_32x32x16_bf16(aa[acur][0], bb[bcur], acc[0], 0, 0, 0);
        acc[1] = __builtin_amdgcn_mfma_f32_32x32x16_bf16(aa[acur][1], bb[bcur], acc[1], 0, 0, 0);
        // B-prefetch for ks+8 into the slot JUST consumed ((ks+8)&7 == bcur)
        if (ks < 24)
            bb[bcur] = *(const bf16x8*)(wf + ((ks + 8 + koff) & 31) * 512);
    }

    // ---- epilogue: tanh(acc + b + hlast) * v, reduce over this wave's 32 cols.
    // C/D of 32x32: col = lane&31, row = (reg&3) + 8*(reg>>2) + 4*(lane>>5).
    const float* hlast = hidden + (size_t)((L_ - 1) * B_ + batch) * H_;
    const int n  = wave * 32 + l31;
    const float bn = bias[n] + hlast[n];
    const float vn = v[n];

    __syncthreads();                 // done reading Alds; reuse as scratch
    float*   sred  = (float*)Alds;            // 16 waves x 64 rows = 4 KB
    float*   pbuf  = sred + 1024;             // 64 softmax numerators
    floatx4* pvred = (floatx4*)(pbuf + 64);   // 8 x 128 floatx4 = 16 KB

    #pragma unroll
    for (int mt = 0; mt < 2; ++mt)
        #pragma unroll
        for (int rg = 0; rg < 16; ++rg) {
            float s = fast_tanh(acc[mt][rg] + bn) * vn;
            s += __shfl_xor(s, 1);
            s += __shfl_xor(s, 2);
            s += __shfl_xor(s, 4);
            s += __shfl_xor(s, 8);
            s += __shfl_xor(s, 16);
            if (l31 == 0) {
                int row = (rg & 3) + 8 * (rg >> 2) + 4 * half;
                sred[wave * 64 + mt * 32 + row] = s;
            }
        }
    __syncthreads();

    // ---- flash-style local softmax numerators on the block's 64 rows ----
    if (tid < 64) {   // wave 0, full 64-lane wave
        float sc = 0.0f;
        #pragma unroll
        for (int w = 0; w < 16; ++w) sc += sred[w * 64 + tid];
        scores[m0 + tid] = sc;
        float mx = sc;
        #pragma unroll
        for (int off = 32; off >= 1; off >>= 1) mx = fmaxf(mx, __shfl_xor(mx, off));
        float p = __expf(sc - mx);
        pbuf[tid] = p;
        float sm = p;
        #pragma unroll
        for (int off = 32; off >= 1; off >>= 1) sm += __shfl_xor(sm, off);
        if (tid == 0) { lmaxg[blockIdx.x] = mx; lsumg[blockIdx.x] = sm; }
    }
    __syncthreads();

    // ---- partial context: pc[h] = sum_{s<64} p_s * out[m0+s][h] (fp32).
    // 8-way s-split across 1024 threads; NONTEMPORAL so the re-read does not
    // evict Wf from L2 (data is read-once, already L2/L3-hot from staging).
    {
        const int c4 = tid & 127;        // float4 column
        const int sg = tid >> 7;         // 0..7 -> 8-row group
        const floatx4* op = (const floatx4*)(outT + (size_t)(m0 + sg * 8) * H_) + c4;
        floatx4 a = (floatx4)(0.0f);
        #pragma unroll
        for (int j = 0; j < 8; ++j)
            a += pbuf[sg * 8 + j] * __builtin_nontemporal_load(op + (size_t)j * 128);
        pvred[sg * 128 + c4] = a;
    }
    __syncthreads();
    if (tid < 128) {
        floatx4 r = (floatx4)(0.0f);
        #pragma unroll
        for (int sg = 0; sg < 8; ++sg) r += pvred[sg * 128 + tid];
        *(floatx4*)&pc[(size_t)blockIdx.x * H_ + tid * 4] = r;
    }
}

// ---------------- kernel 2: softmax over S per batch (writes attn output) -------
__global__ __launch_bounds__(256) void softmax_kernel(const float* __restrict__ scores,
                                                      float* __restrict__ attn) {
    __shared__ float red[4];
    int b = blockIdx.x, tid = threadIdx.x;
    const float* row = scores + (size_t)b * S_;
    float vals[16];
    float mx = -3.4e38f;
    #pragma unroll
    for (int i = 0; i < 16; ++i) { vals[i] = row[i * 256 + tid]; mx = fmaxf(mx, vals[i]); }
    #pragma unroll
    for (int off = 32; off >= 1; off >>= 1) mx = fmaxf(mx, __shfl_xor(mx, off));
    if ((tid & 63) == 0) red[tid >> 6] = mx;
    __syncthreads();
    mx = fmaxf(fmaxf(red[0], red[1]), fmaxf(red[2], red[3]));
    __syncthreads();
    float sum = 0.f;
    #pragma unroll
    for (int i = 0; i < 16; ++i) { vals[i] = __expf(vals[i] - mx); sum += vals[i]; }
    #pragma unroll
    for (int off = 32; off >= 1; off >>= 1) sum += __shfl_xor(sum, off);
    if ((tid & 63) == 0) red[tid >> 6] = sum;
    __syncthreads();
    float inv = 1.0f / (red[0] + red[1] + red[2] + red[3]);
    #pragma unroll
    for (int i = 0; i < 16; ++i) attn[(size_t)b * S_ + i * 256 + tid] = vals[i] * inv;
}

// ---------------- kernel 3: combine 64 per-block partials -> ctx ----------------
// ctx[b][h] = ( sum_j exp(lmax_j - gmax) * pc[b*64+j][h] ) / gsum,
// gsum = sum_j exp(lmax_j - gmax) * lsum_j.   Reads only 4 MB total.
__global__ __launch_bounds__(256) void context_final(const float* __restrict__ pc,
                                                     const float* __restrict__ lmaxg,
                                                     const float* __restrict__ lsumg,
                                                     float* __restrict__ ctx) {
    __shared__ float e_sh[64];
    __shared__ float inv_sh;
    int b = blockIdx.x, tid = threadIdx.x;
    if (tid < 64) {    // wave 0: 64 per-block stats of this batch
        float lm = lmaxg[b * 64 + tid];
        float mx = lm;
        #pragma unroll
        for (int off = 32; off >= 1; off >>= 1) mx = fmaxf(mx, __shfl_xor(mx, off));
        float e = __expf(lm - mx);
        e_sh[tid] = e;
        float gs = e * lsumg[b * 64 + tid];
        #pragma unroll
        for (int off = 32; off >= 1; off >>= 1) gs += __shfl_xor(gs, off);
        if (tid == 0) inv_sh = 1.0f / gs;
    }
    __syncthreads();
    float inv = inv_sh;
    const floatx2* pp = (const floatx2*)(pc + (size_t)b * 64 * H_) + tid;
    floatx2 a = (floatx2)(0.0f);
    #pragma unroll 8
    for (int j = 0; j < 64; ++j) {
        floatx2 q = __builtin_nontemporal_load(pp + (size_t)j * 256);
        a += e_sh[j] * q;
    }
    floatx2 r = a * inv;
    *(floatx2*)&ctx[(size_t)b * H_ + tid * 2] = r;
}

extern "C" void kernel_launch(void* const* d_in, const int* in_sizes, int n_in,
                              void* d_out, int out_size, void* d_ws, size_t ws_size,
                              hipStream_t stream) {
    const float* outT   = (const float*)d_in[0];  // (B,S,H)
    const float* hidden = (const float*)d_in[1];  // (L,B,H)
    const float* W      = (const float*)d_in[2];  // (H,H)
    const float* bias   = (const float*)d_in[3];  // (H)
    const float* v      = (const float*)d_in[4];  // (H)

    float* ctx    = (float*)d_out;                // (B,H)
    float* attn   = (float*)d_out + B_ * H_;      // (B,S)

    const int NBLK = M_ / MT;                     // 2048
    float* scores = (float*)d_ws;                                   // 512 KB
    bf16*  Wf     = (bf16*)((char*)d_ws + (size_t)M_ * 4);          // 512 KB
    float* pc     = (float*)((char*)d_ws + (size_t)M_ * 4 + (size_t)H_ * H_ * 2); // 4 MB
    float* lmaxg  = pc + (size_t)NBLK * H_;                         // 8 KB
    float* lsumg  = lmaxg + NBLK;                                   // 8 KB

    convert_Wfrag<<<128, 256, 0, stream>>>(W, Wf);
    scores_kernel<<<NBLK, 1024, 0, stream>>>(outT, Wf, bias, hidden, v,
                                             scores, pc, lmaxg, lsumg);
    softmax_kernel<<<B_, 256, 0, stream>>>(scores, attn);
    context_final<<<B_, 256, 0, stream>>>(pc, lmaxg, lsumg, ctx);
}

// Round 8
// 470.535 us; speedup vs baseline: 1.0816x; 1.0767x over previous
//
#include <hip/hip_runtime.h>
#include <hip/hip_bf16.h>

#define B_ 32
#define S_ 4096
#define H_ 512
#define M_ (B_ * S_)   // 131072
#define L_ 2

typedef __bf16 bf16;
typedef bf16 bf16x8 __attribute__((ext_vector_type(8)));
typedef float floatx2 __attribute__((ext_vector_type(2)));
typedef float floatx4 __attribute__((ext_vector_type(4)));
typedef float floatx16 __attribute__((ext_vector_type(16)));

__device__ inline bf16 f2b(float f) { return (bf16)f; }

__device__ inline float fast_tanh(float x) {
    float xc = fminf(15.0f, fmaxf(-15.0f, x));
    float e = __expf(2.0f * xc);
    return (e - 1.0f) * __builtin_amdgcn_rcpf(e + 1.0f);
}

// ---------------- kernel 0: W (H,H) fp32 -> bf16 MFMA-fragment-major ----------------
// Fragment (nt, ks) = 32 W-rows x 16 k, stored as 64 lanes x 16B contiguous (1 KB):
// lane l holds W[nt*32 + (l&31)][ks*16 + (l>>5)*8 .. +8).
__global__ __launch_bounds__(256) void convert_Wfrag(const float* __restrict__ W,
                                                     bf16* __restrict__ Wf) {
    int gid  = blockIdx.x * 256 + threadIdx.x;   // 0..32767
    int lane = gid & 63;
    int ks   = (gid >> 6) & 31;
    int nt   = gid >> 11;                        // 0..15
    int row  = nt * 32 + (lane & 31);
    int col  = ks * 16 + (lane >> 5) * 8;
    const float* src = W + (size_t)row * H_ + col;
    floatx4 f0 = *(const floatx4*)src;
    floatx4 f1 = *(const floatx4*)(src + 4);
    bf16x8 p = { f2b(f0[0]), f2b(f0[1]), f2b(f0[2]), f2b(f0[3]),
                 f2b(f1[0]), f2b(f1[1]), f2b(f1[2]), f2b(f1[3]) };
    *(bf16x8*)(Wf + (size_t)gid * 8) = p;
}

// ---------------- kernel 1: fused scores + partial context (flash-style) --------
// 16 waves (1024 threads), wave w owns n in [w*32, w*32+32).
// OPERAND-SWAPPED MFMA: acc = mfma(Wfrag, outfrag) computes D[n][m] so the
// output COLUMN is m (lane&31) and the 16 regs are n-values. The n-reduction
// (dot with v after tanh) is then a per-lane serial sum: 0 shuffles instead of
// 160 shfl_xor + 160 adds per thread (the DS-pipe cost that bounded r1-r7).
// bias/hlast/v are reg-indexed -> 4 KB LDS table bv[n] = {bias+hlast, v}.
#define MT 64

__global__ __launch_bounds__(1024, 4) void scores_kernel(
    const float* __restrict__ outT,   // (M, 512)
    const bf16*  __restrict__ Wf,     // fragment-major W (512 KB)
    const float* __restrict__ bias,   // (512)
    const float* __restrict__ hidden, // (L, B, 512)
    const float* __restrict__ v,      // (512)
    float* __restrict__ scores,       // (M)
    float* __restrict__ pc,           // (M/MT, 512) partial context
    float* __restrict__ lmaxg,        // (M/MT)
    float* __restrict__ lsumg)        // (M/MT)
{
    __shared__ bf16 Alds[MT * 512];   // 64 KB, fragment-major
    __shared__ float bv[2 * H_];      // 4 KB: {bias+hlast, v} per n

    const int tid  = threadIdx.x;
    const int wave = tid >> 6;        // 0..15 == n-window owned by this wave
    const int lane = tid & 63;
    const int l31  = lane & 31;
    const int half = lane >> 5;       // 0..1

    const int m0    = blockIdx.x * MT;
    const int batch = m0 >> 12;       // m0 / S_
    const int koff  = (wave * 2) & 31;  // per-wave K rotation

    // per-lane Wf base: frag(nt, ks) at nt*16384 + ks*512 elements
    const bf16* wf = Wf + (size_t)wave * 16384 + lane * 8;

    // B-ring prologue (depth 8) issued BEFORE staging: L2 latency overlaps stage
    bf16x8 bb[8];
    #pragma unroll
    for (int p = 0; p < 8; ++p)
        bb[p] = *(const bf16x8*)(wf + ((p + koff) & 31) * 512);

    // fill bv table (before the staging barrier; covered by it)
    if (tid < H_) {
        float bh = bias[tid] + hidden[(size_t)((L_ - 1) * B_ + batch) * H_ + tid];
        bv[tid * 2]     = bh;
        bv[tid * 2 + 1] = v[tid];
    }

    // ---- stage A: 64 rows x 512 fp32 -> bf16 fragment-major LDS.
    // A-frag (mt, ks): lane l holds A[mt*32 + (l&31)][ks*16 + (l>>5)*8 ..+8)
    // at slot = (l>>5)*32 + ((l&31) + ks)&31  (rotation kills write conflicts).
    {
        const floatx4* src = (const floatx4*)(outT + (size_t)m0 * H_);
        #pragma unroll
        for (int it = 0; it < 4; ++it) {
            int idx = it * 1024 + tid;    // 16B-block index: r = row, j = k-block
            int r   = idx >> 6;
            int j   = idx & 63;
            floatx4 f0 = __builtin_nontemporal_load(src + idx * 2);
            floatx4 f1 = __builtin_nontemporal_load(src + idx * 2 + 1);
            bf16x8 p = { f2b(f0[0]), f2b(f0[1]), f2b(f0[2]), f2b(f0[3]),
                         f2b(f1[0]), f2b(f1[1]), f2b(f1[2]), f2b(f1[3]) };
            int frag = (r >> 5) * 32 + (j >> 1);
            int slot = (j & 1) * 32 + ((r + (j >> 1)) & 31);
            *(bf16x8*)&Alds[frag * 512 + slot * 8] = p;
        }
    }
    __syncthreads();

    floatx16 acc[2];
    acc[0] = (floatx16)(0.0f);
    acc[1] = (floatx16)(0.0f);

    // depth-4 A ring, prefetch distance 2 (two ds_reads in flight per mt)
    bf16x8 aa[4][2];
    #pragma unroll
    for (int p = 0; p < 2; ++p) {
        const int kk = (p + koff) & 31;
        const int rot = (l31 + kk) & 31;
        #pragma unroll
        for (int mt = 0; mt < 2; ++mt)
            aa[p][mt] = *(const bf16x8*)
                &Alds[(mt * 32 + kk) * 512 + (half * 32 + rot) * 8];
    }

    #pragma unroll
    for (int ks = 0; ks < 32; ++ks) {
        const int bcur = ks & 7;
        const int acur = ks & 3;
        // A-prefetch for ks+2: ds_read latency hidden behind 2 ksteps of issue
        if (ks < 30) {
            const int kk = (ks + 2 + koff) & 31;
            const int rot = (l31 + kk) & 31;
            #pragma unroll
            for (int mt = 0; mt < 2; ++mt)
                aa[(ks + 2) & 3][mt] = *(const bf16x8*)
                    &Alds[(mt * 32 + kk) * 512 + (half * 32 + rot) * 8];
        }
        // SWAPPED operands: D[n][m] — out-fragment as B-operand (same reg layout)
        acc[0] = __builtin_amdgcn_mfma_f32_32x32x16_bf16(bb[bcur], aa[acur][0], acc[0], 0, 0, 0);
        acc[1] = __builtin_amdgcn_mfma_f32_32x32x16_bf16(bb[bcur], aa[acur][1], acc[1], 0, 0, 0);
        // B-prefetch for ks+8 into the slot JUST consumed ((ks+8)&7 == bcur)
        if (ks < 24)
            bb[bcur] = *(const bf16x8*)(wf + ((ks + 8 + koff) & 31) * 512);
    }

    // ---- epilogue: per-lane serial n-reduction (no shuffles).
    // D[n][m]: m = mt*32 + (lane&31); n = wave*32 + (rg&3) + 8*(rg>>2) + 4*half.
    float p0 = 0.0f, p1 = 0.0f;
    #pragma unroll
    for (int rg = 0; rg < 16; ++rg) {
        const int nl = (rg & 3) + 8 * (rg >> 2) + 4 * half;
        floatx2 bvv = *(const floatx2*)&bv[(wave * 32 + nl) * 2];  // broadcast read
        p0 += fast_tanh(acc[0][rg] + bvv.x) * bvv.y;
        p1 += fast_tanh(acc[1][rg] + bvv.x) * bvv.y;
    }
    // merge the two k-halves (other 16 n's of this wave's window)
    p0 += __shfl_xor(p0, 32);
    p1 += __shfl_xor(p1, 32);

    __syncthreads();                 // done reading Alds; reuse as scratch
    float*   sred  = (float*)Alds;            // 16 waves x 64 rows = 4 KB
    float*   pbuf  = sred + 1024;             // 64 softmax numerators
    floatx4* pvred = (floatx4*)(pbuf + 64);   // 8 x 128 floatx4 = 16 KB

    if (lane < 32) {
        sred[wave * 64 + l31]      = p0;      // m = l31       (mt=0)
        sred[wave * 64 + 32 + l31] = p1;      // m = 32 + l31  (mt=1)
    }
    __syncthreads();

    // ---- flash-style local softmax numerators on the block's 64 rows ----
    if (tid < 64) {   // wave 0, full 64-lane wave
        float sc = 0.0f;
        #pragma unroll
        for (int w = 0; w < 16; ++w) sc += sred[w * 64 + tid];
        scores[m0 + tid] = sc;
        float mx = sc;
        #pragma unroll
        for (int off = 32; off >= 1; off >>= 1) mx = fmaxf(mx, __shfl_xor(mx, off));
        float p = __expf(sc - mx);
        pbuf[tid] = p;
        float sm = p;
        #pragma unroll
        for (int off = 32; off >= 1; off >>= 1) sm += __shfl_xor(sm, off);
        if (tid == 0) { lmaxg[blockIdx.x] = mx; lsumg[blockIdx.x] = sm; }
    }
    __syncthreads();

    // ---- partial context: pc[h] = sum_{s<64} p_s * out[m0+s][h] (fp32).
    // 8-way s-split across 1024 threads; NONTEMPORAL so the re-read does not
    // evict Wf from L2 (data is read-once, already L2/L3-hot from staging).
    {
        const int c4 = tid & 127;        // float4 column
        const int sg = tid >> 7;         // 0..7 -> 8-row group
        const floatx4* op = (const floatx4*)(outT + (size_t)(m0 + sg * 8) * H_) + c4;
        floatx4 a = (floatx4)(0.0f);
        #pragma unroll
        for (int j = 0; j < 8; ++j)
            a += pbuf[sg * 8 + j] * __builtin_nontemporal_load(op + (size_t)j * 128);
        pvred[sg * 128 + c4] = a;
    }
    __syncthreads();
    if (tid < 128) {
        floatx4 r = (floatx4)(0.0f);
        #pragma unroll
        for (int sg = 0; sg < 8; ++sg) r += pvred[sg * 128 + tid];
        *(floatx4*)&pc[(size_t)blockIdx.x * H_ + tid * 4] = r;
    }
}

// ---------------- kernel 2: softmax over S per batch (writes attn output) -------
__global__ __launch_bounds__(256) void softmax_kernel(const float* __restrict__ scores,
                                                      float* __restrict__ attn) {
    __shared__ float red[4];
    int b = blockIdx.x, tid = threadIdx.x;
    const float* row = scores + (size_t)b * S_;
    float vals[16];
    float mx = -3.4e38f;
    #pragma unroll
    for (int i = 0; i < 16; ++i) { vals[i] = row[i * 256 + tid]; mx = fmaxf(mx, vals[i]); }
    #pragma unroll
    for (int off = 32; off >= 1; off >>= 1) mx = fmaxf(mx, __shfl_xor(mx, off));
    if ((tid & 63) == 0) red[tid >> 6] = mx;
    __syncthreads();
    mx = fmaxf(fmaxf(red[0], red[1]), fmaxf(red[2], red[3]));
    __syncthreads();
    float sum = 0.f;
    #pragma unroll
    for (int i = 0; i < 16; ++i) { vals[i] = __expf(vals[i] - mx); sum += vals[i]; }
    #pragma unroll
    for (int off = 32; off >= 1; off >>= 1) sum += __shfl_xor(sum, off);
    if ((tid & 63) == 0) red[tid >> 6] = sum;
    __syncthreads();
    float inv = 1.0f / (red[0] + red[1] + red[2] + red[3]);
    #pragma unroll
    for (int i = 0; i < 16; ++i) attn[(size_t)b * S_ + i * 256 + tid] = vals[i] * inv;
}

// ---------------- kernel 3: combine 64 per-block partials -> ctx ----------------
// ctx[b][h] = ( sum_j exp(lmax_j - gmax) * pc[b*64+j][h] ) / gsum,
// gsum = sum_j exp(lmax_j - gmax) * lsum_j.   Reads only 4 MB total.
__global__ __launch_bounds__(256) void context_final(const float* __restrict__ pc,
                                                     const float* __restrict__ lmaxg,
                                                     const float* __restrict__ lsumg,
                                                     float* __restrict__ ctx) {
    __shared__ float e_sh[64];
    __shared__ float inv_sh;
    int b = blockIdx.x, tid = threadIdx.x;
    if (tid < 64) {    // wave 0: 64 per-block stats of this batch
        float lm = lmaxg[b * 64 + tid];
        float mx = lm;
        #pragma unroll
        for (int off = 32; off >= 1; off >>= 1) mx = fmaxf(mx, __shfl_xor(mx, off));
        float e = __expf(lm - mx);
        e_sh[tid] = e;
        float gs = e * lsumg[b * 64 + tid];
        #pragma unroll
        for (int off = 32; off >= 1; off >>= 1) gs += __shfl_xor(gs, off);
        if (tid == 0) inv_sh = 1.0f / gs;
    }
    __syncthreads();
    float inv = inv_sh;
    const floatx2* pp = (const floatx2*)(pc + (size_t)b * 64 * H_) + tid;
    floatx2 a = (floatx2)(0.0f);
    #pragma unroll 8
    for (int j = 0; j < 64; ++j) {
        floatx2 q = __builtin_nontemporal_load(pp + (size_t)j * 256);
        a += e_sh[j] * q;
    }
    floatx2 r = a * inv;
    *(floatx2*)&ctx[(size_t)b * H_ + tid * 2] = r;
}

extern "C" void kernel_launch(void* const* d_in, const int* in_sizes, int n_in,
                              void* d_out, int out_size, void* d_ws, size_t ws_size,
                              hipStream_t stream) {
    const float* outT   = (const float*)d_in[0];  // (B,S,H)
    const float* hidden = (const float*)d_in[1];  // (L,B,H)
    const float* W      = (const float*)d_in[2];  // (H,H)
    const float* bias   = (const float*)d_in[3];  // (H)
    const float* v      = (const float*)d_in[4];  // (H)

    float* ctx    = (float*)d_out;                // (B,H)
    float* attn   = (float*)d_out + B_ * H_;      // (B,S)

    const int NBLK = M_ / MT;                     // 2048
    float* scores = (float*)d_ws;                                   // 512 KB
    bf16*  Wf     = (bf16*)((char*)d_ws + (size_t)M_ * 4);          // 512 KB
    float* pc     = (float*)((char*)d_ws + (size_t)M_ * 4 + (size_t)H_ * H_ * 2); // 4 MB
    float* lmaxg  = pc + (size_t)NBLK * H_;                         // 8 KB
    float* lsumg  = lmaxg + NBLK;                                   // 8 KB

    convert_Wfrag<<<128, 256, 0, stream>>>(W, Wf);
    scores_kernel<<<NBLK, 1024, 0, stream>>>(outT, Wf, bias, hidden, v,
                                             scores, pc, lmaxg, lsumg);
    softmax_kernel<<<B_, 256, 0, stream>>>(scores, attn);
    context_final<<<B_, 256, 0, stream>>>(pc, lmaxg, lsumg, ctx);
}